// Round 2
// baseline (38.234 us; speedup 1.0000x reference)
//
#include <hip/hip_runtime.h>

#define BATCH 64
#define IMH 256
#define IMW 256
#define CIN 512
#define NH 128

// Kernel 1: per-batch MLP -> alpha + 9 sigmoid kernel weights.
// One block per batch element, 512 threads = 8 waves.
// Each wave owns output rows; lanes stride the dot-product dimension so
// weight loads are 64-lane coalesced (256B/instr), reduced via shuffles.
__global__ __launch_bounds__(512) void mlp_kernel(
        const float* __restrict__ features,
        const float* __restrict__ W0, const float* __restrict__ b0,
        const float* __restrict__ W1, const float* __restrict__ b1,
        const float* __restrict__ W2, const float* __restrict__ b2,
        float* __restrict__ ak /* [BATCH][10] */) {
    const int b    = blockIdx.x;
    const int t    = threadIdx.x;   // 0..511
    const int wave = t >> 6;        // 0..7
    const int lane = t & 63;

    __shared__ float f[CIN];
    __shared__ float h0[NH];
    __shared__ float h1[NH];

    f[t] = features[b * CIN + t];
    __syncthreads();

    // ---- layer 0: h0[r] = relu(dot(f, W0[r,:512]) + b0[r]), 16 rows/wave ----
    #pragma unroll 2
    for (int r0 = 0; r0 < 16; ++r0) {
        const int r = wave * 16 + r0;
        const float* w = W0 + r * CIN;
        float acc = 0.f;
        #pragma unroll
        for (int k = 0; k < CIN / 64; ++k)
            acc = fmaf(w[lane + 64 * k], f[lane + 64 * k], acc);
        #pragma unroll
        for (int off = 32; off > 0; off >>= 1)
            acc += __shfl_down(acc, off);
        if (lane == 0) h0[r] = fmaxf(acc + b0[r], 0.f);
    }
    __syncthreads();

    // ---- layer 1: h1[r] = relu(dot(h0, W1[r,:128]) + b1[r]), 16 rows/wave ----
    #pragma unroll 2
    for (int r0 = 0; r0 < 16; ++r0) {
        const int r = wave * 16 + r0;
        const float* w = W1 + r * NH;
        float acc = 0.f;
        #pragma unroll
        for (int k = 0; k < NH / 64; ++k)
            acc = fmaf(w[lane + 64 * k], h0[lane + 64 * k], acc);
        #pragma unroll
        for (int off = 32; off > 0; off >>= 1)
            acc += __shfl_down(acc, off);
        if (lane == 0) h1[r] = fmaxf(acc + b1[r], 0.f);
    }
    __syncthreads();

    // ---- layer 2: 10 outputs; wave w handles rows w, w+8 ----
    for (int r = wave; r < 10; r += 8) {
        const float* w = W2 + r * NH;
        float acc = 0.f;
        #pragma unroll
        for (int k = 0; k < NH / 64; ++k)
            acc = fmaf(w[lane + 64 * k], h1[lane + 64 * k], acc);
        #pragma unroll
        for (int off = 32; off > 0; off >>= 1)
            acc += __shfl_down(acc, off);
        if (lane == 0) {
            float beta = acc + b2[r];
            float outv;
            if (r == 0) {
                outv = beta;                       // alpha
            } else {
                beta += (r == 5) ? 5.f : -5.f;     // identity bias (center tap +5)
                outv = 1.f / (1.f + __expf(-beta)); // sigmoid
            }
            ak[b * 10 + r] = outv;
        }
    }
}

// Kernel 2: 3x3 smooth-max pooling, 4 px/thread via float4.
// grid = (IMH/4, BATCH), block = 256 (4 rows x 64 float4-columns).
// Per input row a thread loads 6 values and computes 6 exps shared by its
// 4 output pixels (4.5 exps/px vs 9 naive). OOB taps: p=0 -> e=1, which
// reproduces the reference's zero-padding exactly.
__global__ __launch_bounds__(256) void smoothmax_kernel(
        const float* __restrict__ x,
        const float* __restrict__ ak,
        float* __restrict__ out) {
    const int t   = threadIdx.x;
    const int b   = blockIdx.y;
    const int row = (blockIdx.x << 2) + (t >> 6);  // 0..255
    const int c0  = (t & 63) << 2;                 // 0,4,...,252

    const float* akb = ak + b * 10;
    const float alpha = akb[0];
    float kern[9];
    #pragma unroll
    for (int i = 0; i < 9; ++i) kern[i] = akb[1 + i];

    const float* xb = x + ((size_t)b << 16);

    float num[4] = {0.f, 0.f, 0.f, 0.f};
    float den[4] = {0.f, 0.f, 0.f, 0.f};

    #pragma unroll
    for (int dy = -1; dy <= 1; ++dy) {
        const int rr = row + dy;
        float p[6];
        if ((unsigned)rr < (unsigned)IMH) {
            const float* xr = xb + rr * IMW;
            const float4 v = *reinterpret_cast<const float4*>(xr + c0);
            p[0] = (c0 == 0)          ? 0.f : xr[c0 - 1];
            p[1] = v.x; p[2] = v.y; p[3] = v.z; p[4] = v.w;
            p[5] = (c0 == IMW - 4)    ? 0.f : xr[c0 + 4];
        } else {
            #pragma unroll
            for (int j = 0; j < 6; ++j) p[j] = 0.f;
        }
        float e[6];
        #pragma unroll
        for (int j = 0; j < 6; ++j) e[j] = __expf(alpha * p[j]);
        const int kr = (dy + 1) * 3;
        #pragma unroll
        for (int i = 0; i < 4; ++i) {
            #pragma unroll
            for (int dx = 0; dx < 3; ++dx) {
                const float wt = e[i + dx] * kern[kr + dx];
                num[i] = fmaf(p[i + dx], wt, num[i]);
                den[i] += wt;
            }
        }
    }

    float4 o;
    o.x = num[0] * __builtin_amdgcn_rcpf(den[0]);
    o.y = num[1] * __builtin_amdgcn_rcpf(den[1]);
    o.z = num[2] * __builtin_amdgcn_rcpf(den[2]);
    o.w = num[3] * __builtin_amdgcn_rcpf(den[3]);
    *reinterpret_cast<float4*>(out + ((size_t)b << 16) + row * IMW + c0) = o;
}

extern "C" void kernel_launch(void* const* d_in, const int* in_sizes, int n_in,
                              void* d_out, int out_size, void* d_ws, size_t ws_size,
                              hipStream_t stream) {
    const float* x        = (const float*)d_in[0];
    const float* features = (const float*)d_in[1];
    const float* W0       = (const float*)d_in[2];
    const float* b0       = (const float*)d_in[3];
    const float* W1       = (const float*)d_in[4];
    const float* b1       = (const float*)d_in[5];
    const float* W2       = (const float*)d_in[6];
    const float* b2       = (const float*)d_in[7];
    float* out = (float*)d_out;
    float* ak  = (float*)d_ws;  // BATCH*10 floats

    mlp_kernel<<<BATCH, 512, 0, stream>>>(features, W0, b0, W1, b1, W2, b2, ak);
    smoothmax_kernel<<<dim3(IMH / 4, BATCH), 256, 0, stream>>>(x, ak, out);
}